// Round 1
// baseline (440.258 us; speedup 1.0000x reference)
//
#include <hip/hip_runtime.h>
#include <hip/hip_bf16.h>

typedef __attribute__((ext_vector_type(8))) short bf16x8;
typedef __attribute__((ext_vector_type(4))) float f32x4;
typedef __attribute__((ext_vector_type(8))) unsigned short u16x8;

#define RR 128
#define CC 256
#define EE 768
#define HH 12
#define DKK 64
#define MTOK 32768
#define NQKV 2304

__device__ __forceinline__ unsigned short f2bf(float f) {
  union { float f; unsigned u; } v; v.f = f;
  unsigned u = v.u;
  unsigned r = (u + 0x7fffu + ((u >> 16) & 1u)) >> 16;
  return (unsigned short)r;
}

__device__ __forceinline__ void gload16(const unsigned short* g, unsigned short* l) {
  __builtin_amdgcn_global_load_lds((const __attribute__((address_space(1))) void*)g,
                                   (__attribute__((address_space(3))) void*)l, 16, 0, 0);
}

// ---------------- cast fp32 -> bf16, 8 elements/thread ----------------
__global__ void cast_f32_to_bf16(const float* __restrict__ src,
                                 unsigned short* __restrict__ dst, int n8) {
  int t = blockIdx.x * 256 + threadIdx.x;
  if (t >= n8) return;
  const float4* s = (const float4*)src + (size_t)t * 2;
  float4 a = s[0], b = s[1];
  u16x8 o;
  o[0] = f2bf(a.x); o[1] = f2bf(a.y); o[2] = f2bf(a.z); o[3] = f2bf(a.w);
  o[4] = f2bf(b.x); o[5] = f2bf(b.y); o[6] = f2bf(b.z); o[7] = f2bf(b.w);
  *(u16x8*)(dst + (size_t)t * 8) = o;
}

// ---------------- GEMM: C[M][N] = A[M][768] * B[N][768]^T (+bias) ----------------
// 128x128 tile, BK=64, 4 waves (2x2), double-buffered global_load_lds staging.
// QKV==1: out bf16 [M][2304], (acc+bias)*scale, scale=0.125 for q block.
// QKV==0: out fp32 [M][768], acc+bias.
template <int QKV>
__global__ __launch_bounds__(256, 2) void gemm_bt(
    const unsigned short* __restrict__ A, const unsigned short* __restrict__ Bw,
    void* __restrict__ OutP, const float* __restrict__ bias0,
    const float* __restrict__ bias1, const float* __restrict__ bias2) {
  __shared__ unsigned short la[2][8192];
  __shared__ unsigned short lb[2][8192];
  const int bid = blockIdx.x;
  const int bm = bid & 255;  // M/128 = 256
  const int bn = bid >> 8;
  const int r0 = bm << 7, c0 = bn << 7;
  const int tid = threadIdx.x;
  const int wid = tid >> 6, lane = tid & 63;
  const int wr = wid >> 1, wc = wid & 1;
  const int lr = lane & 15, lg = lane >> 4;

  const int srow = (wid << 5) + (lane >> 3);
  const int scol = (lane & 7) << 3;
  const unsigned short* ga = A + (size_t)(r0 + srow) * EE + scol;
  const unsigned short* gb = Bw + (size_t)(c0 + srow) * EE + scol;

  f32x4 acc[4][4] = {};

#define STAGE(buf, kt)                                              \
  do {                                                              \
    const unsigned short* pa = ga + (kt) * 64;                      \
    const unsigned short* pb = gb + (kt) * 64;                      \
    _Pragma("unroll") for (int q2 = 0; q2 < 4; ++q2) {              \
      gload16(pa + q2 * 8 * EE, &la[buf][(wid * 4 + q2) * 512]);    \
      gload16(pb + q2 * 8 * EE, &lb[buf][(wid * 4 + q2) * 512]);    \
    }                                                               \
  } while (0)

#define COMPUTE(buf)                                                          \
  do {                                                                        \
    const unsigned short* ra = &la[buf][(((wr << 6) + lr) << 6) + (lg << 3)]; \
    const unsigned short* rb = &lb[buf][(((wc << 6) + lr) << 6) + (lg << 3)]; \
    _Pragma("unroll") for (int kk = 0; kk < 2; ++kk) {                        \
      bf16x8 af[4], bfr[4];                                                   \
      _Pragma("unroll") for (int m = 0; m < 4; ++m)                           \
          af[m] = *(const bf16x8*)(ra + m * 1024 + kk * 32);                  \
      _Pragma("unroll") for (int n = 0; n < 4; ++n)                           \
          bfr[n] = *(const bf16x8*)(rb + n * 1024 + kk * 32);                 \
      _Pragma("unroll") for (int m = 0; m < 4; ++m)                           \
          _Pragma("unroll") for (int n = 0; n < 4; ++n)                       \
              acc[m][n] = __builtin_amdgcn_mfma_f32_16x16x32_bf16(            \
                  af[m], bfr[n], acc[m][n], 0, 0, 0);                         \
    }                                                                         \
  } while (0)

  STAGE(0, 0);
  asm volatile("s_waitcnt vmcnt(0)" ::: "memory");
  __syncthreads();
  int cur = 0;
  for (int t = 0; t < 11; ++t) {
    STAGE(cur ^ 1, t + 1);
    COMPUTE(cur);
    __syncthreads();
    cur ^= 1;
  }
  COMPUTE(cur);
#undef STAGE
#undef COMPUTE

  if constexpr (QKV == 1) {
    const int mat = c0 / 768;
    const float* bp = mat == 0 ? bias0 : (mat == 1 ? bias1 : bias2);
    const float scale = mat == 0 ? 0.125f : 1.0f;
    const int cb = c0 - mat * 768;
    unsigned short* out = (unsigned short*)OutP;
#pragma unroll
    for (int n = 0; n < 4; ++n) {
      int col = (wc << 6) + (n << 4) + lr;
      float bvv = bp[cb + col];
#pragma unroll
      for (int m = 0; m < 4; ++m) {
#pragma unroll
        for (int r = 0; r < 4; ++r) {
          int row = r0 + (wr << 6) + (m << 4) + (lg << 2) + r;
          out[(size_t)row * NQKV + c0 + col] = f2bf((acc[m][n][r] + bvv) * scale);
        }
      }
    }
  } else {
    float* out = (float*)OutP;
#pragma unroll
    for (int n = 0; n < 4; ++n) {
      int col = (wc << 6) + (n << 4) + lr;
      float bvv = bias0[c0 + col];
#pragma unroll
      for (int m = 0; m < 4; ++m) {
#pragma unroll
        for (int r = 0; r < 4; ++r) {
          int row = r0 + (wr << 6) + (m << 4) + (lg << 2) + r;
          out[(size_t)row * EE + c0 + col] = acc[m][n][r] + bvv;
        }
      }
    }
  }
}

// ---------------- attention per (c,h): 128 queries x 128 keys x 64 dk --------
__global__ __launch_bounds__(256, 2) void attn_kernel(
    const unsigned short* __restrict__ qkv, const unsigned char* __restrict__ pmask,
    float* __restrict__ probs, unsigned short* __restrict__ ctx) {
  __shared__ unsigned short ks[128 * 72];
  __shared__ unsigned short vt[64 * 136];
  __shared__ unsigned short ps[128 * 136];
  const int bx = blockIdx.x;
  const int c = bx / HH, h = bx - (bx / HH) * HH;
  const int tid = threadIdx.x;
  const int wid = tid >> 6, lane = tid & 63;
  const int lr = lane & 15, lg = lane >> 4;
  const int wr = wid;
  const size_t hoff = (size_t)h * DKK;

  // stage K (row-major, pad 72) and V^T (pad 136)
#pragma unroll
  for (int p = 0; p < 4; ++p) {
    int chunk = p * 256 + tid;
    int j = chunk >> 3, d0 = (chunk & 7) << 3;
    const unsigned short* base = qkv + ((size_t)j * CC + c) * NQKV + hoff;
    bf16x8 kv = *(const bf16x8*)(base + 768 + d0);
    *(bf16x8*)&ks[j * 72 + d0] = kv;
    bf16x8 vv = *(const bf16x8*)(base + 1536 + d0);
#pragma unroll
    for (int u = 0; u < 8; ++u) vt[(d0 + u) * 136 + j] = (unsigned short)vv[u];
  }

  // Q fragments straight from global (already scaled by dk^-0.5 in projection)
  bf16x8 qf[2][2];
#pragma unroll
  for (int m = 0; m < 2; ++m)
#pragma unroll
    for (int kk = 0; kk < 2; ++kk) {
      int qi = (wr << 5) + (m << 4) + lr;
      qf[m][kk] = *(const bf16x8*)(qkv + ((size_t)qi * CC + c) * NQKV + hoff +
                                   kk * 32 + (lg << 3));
    }

  __syncthreads();

  // S = Q K^T  (per wave: 32 rows x 128 cols)
  f32x4 s[2][8] = {};
#pragma unroll
  for (int kk = 0; kk < 2; ++kk) {
    bf16x8 kf[8];
#pragma unroll
    for (int n = 0; n < 8; ++n)
      kf[n] = *(const bf16x8*)&ks[(n * 16 + lr) * 72 + kk * 32 + (lg << 3)];
#pragma unroll
    for (int m = 0; m < 2; ++m)
#pragma unroll
      for (int n = 0; n < 8; ++n)
        s[m][n] = __builtin_amdgcn_mfma_f32_16x16x32_bf16(qf[m][kk], kf[n],
                                                          s[m][n], 0, 0, 0);
  }

  // padding mask: key j masked -> logit = -10000
#pragma unroll
  for (int n = 0; n < 8; ++n) {
    if (pmask[(size_t)(n * 16 + lr) * CC + c] != 0) {
      f32x4 neg = {-10000.0f, -10000.0f, -10000.0f, -10000.0f};
      s[0][n] = neg;
      s[1][n] = neg;
    }
  }

  // softmax over j (8 frags local + 16-lane shuffle reduce)
  float inv_[2][4];
#pragma unroll
  for (int m = 0; m < 2; ++m) {
    f32x4 mx = s[m][0];
#pragma unroll
    for (int n = 1; n < 8; ++n)
#pragma unroll
      for (int r = 0; r < 4; ++r) mx[r] = fmaxf(mx[r], s[m][n][r]);
#pragma unroll
    for (int r = 0; r < 4; ++r) {
      float t = mx[r];
      t = fmaxf(t, __shfl_xor(t, 1));
      t = fmaxf(t, __shfl_xor(t, 2));
      t = fmaxf(t, __shfl_xor(t, 4));
      t = fmaxf(t, __shfl_xor(t, 8));
      mx[r] = t;
    }
    f32x4 sum = {};
#pragma unroll
    for (int n = 0; n < 8; ++n)
#pragma unroll
      for (int r = 0; r < 4; ++r) {
        float e = exp2f((s[m][n][r] - mx[r]) * 1.44269504f);
        s[m][n][r] = e;
        sum[r] += e;
      }
#pragma unroll
    for (int r = 0; r < 4; ++r) {
      float t = sum[r];
      t += __shfl_xor(t, 1);
      t += __shfl_xor(t, 2);
      t += __shfl_xor(t, 4);
      t += __shfl_xor(t, 8);
      inv_[m][r] = __builtin_amdgcn_rcpf(t);
    }
  }

  // write probs (fp32, output 1) and P (bf16) to LDS
  const size_t pbase = ((size_t)h * CC + c) * (size_t)(128 * 128);
#pragma unroll
  for (int m = 0; m < 2; ++m)
#pragma unroll
    for (int n = 0; n < 8; ++n)
#pragma unroll
      for (int r = 0; r < 4; ++r) {
        float pv = s[m][n][r] * inv_[m][r];
        int i = (wr << 5) + (m << 4) + (lg << 2) + r;
        int j = (n << 4) + lr;
        probs[pbase + (size_t)i * 128 + j] = pv;
        ps[i * 136 + j] = f2bf(pv);
      }

  __syncthreads();

  // ctx = P V   (32 rows x 64 d per wave, K=128)
  f32x4 o[2][4] = {};
#pragma unroll
  for (int kk = 0; kk < 4; ++kk) {
    bf16x8 pa[2], vb[4];
#pragma unroll
    for (int m = 0; m < 2; ++m)
      pa[m] = *(const bf16x8*)&ps[((wr << 5) + (m << 4) + lr) * 136 + kk * 32 + (lg << 3)];
#pragma unroll
    for (int n = 0; n < 4; ++n)
      vb[n] = *(const bf16x8*)&vt[((n << 4) + lr) * 136 + kk * 32 + (lg << 3)];
#pragma unroll
    for (int m = 0; m < 2; ++m)
#pragma unroll
      for (int n = 0; n < 4; ++n)
        o[m][n] = __builtin_amdgcn_mfma_f32_16x16x32_bf16(pa[m], vb[n], o[m][n], 0, 0, 0);
  }

  // ctx write (bf16, token-major for the output projection)
#pragma unroll
  for (int m = 0; m < 2; ++m)
#pragma unroll
    for (int n = 0; n < 4; ++n)
#pragma unroll
      for (int r = 0; r < 4; ++r) {
        int i = (wr << 5) + (m << 4) + (lg << 2) + r;
        int d = (n << 4) + lr;
        ctx[((size_t)i * CC + c) * EE + hoff + d] = f2bf(o[m][n][r]);
      }
}

extern "C" void kernel_launch(void* const* d_in, const int* in_sizes, int n_in,
                              void* d_out, int out_size, void* d_ws, size_t ws_size,
                              hipStream_t stream) {
  const float* x = (const float*)d_in[0];
  const unsigned char* pm = (const unsigned char*)d_in[1];
  const float* Wq = (const float*)d_in[2];
  const float* bq = (const float*)d_in[3];
  const float* Wk = (const float*)d_in[4];
  const float* bk = (const float*)d_in[5];
  const float* Wv = (const float*)d_in[6];
  const float* bv = (const float*)d_in[7];
  const float* Wo = (const float*)d_in[8];
  const float* bo = (const float*)d_in[9];

  unsigned short* ws = (unsigned short*)d_ws;
  unsigned short* xb = ws;                       // 25165824 el (x_bf16, later ctx)
  unsigned short* qkv = xb + 25165824;           // 75497472 el
  unsigned short* wqkv = qkv + 75497472;         // 1769472 el (Wq|Wk|Wv)
  unsigned short* wo = wqkv + 1769472;           // 589824 el

  float* outp = (float*)d_out;
  float* probs = outp + 25165824;

  cast_f32_to_bf16<<<12288, 256, 0, stream>>>(x, xb, 3145728);
  cast_f32_to_bf16<<<288, 256, 0, stream>>>(Wq, wqkv, 73728);
  cast_f32_to_bf16<<<288, 256, 0, stream>>>(Wk, wqkv + 589824, 73728);
  cast_f32_to_bf16<<<288, 256, 0, stream>>>(Wv, wqkv + 1179648, 73728);
  cast_f32_to_bf16<<<288, 256, 0, stream>>>(Wo, wo, 73728);

  gemm_bt<1><<<256 * 18, 256, 0, stream>>>(xb, wqkv, (void*)qkv, bq, bk, bv);
  attn_kernel<<<CC * HH, 256, 0, stream>>>(qkv, pm, probs, xb /*ctx*/);
  gemm_bt<0><<<256 * 6, 256, 0, stream>>>(xb, wo, (void*)outp, bo, nullptr, nullptr);
}

// Round 2
// 347.327 us; speedup vs baseline: 1.2676x; 1.2676x over previous
//
#include <hip/hip_runtime.h>
#include <hip/hip_bf16.h>

typedef __attribute__((ext_vector_type(8))) short bf16x8;
typedef __attribute__((ext_vector_type(4))) float f32x4;
typedef __attribute__((ext_vector_type(8))) unsigned short u16x8;

#define RR 128
#define CC 256
#define EE 768
#define HH 12
#define DKK 64
#define NQKV 2304

__device__ __forceinline__ unsigned short f2bf(float f) {
  union { float f; unsigned u; } v; v.f = f;
  unsigned u = v.u;
  unsigned r = (u + 0x7fffu + ((u >> 16) & 1u)) >> 16;
  return (unsigned short)r;
}

__device__ __forceinline__ void gload16(const unsigned short* g, char* l) {
  __builtin_amdgcn_global_load_lds((const __attribute__((address_space(1))) void*)g,
                                   (__attribute__((address_space(3))) void*)l, 16, 0, 0);
}

// ---------------- cast fp32 -> bf16, 8 elements/thread ----------------
__global__ void cast_f32_to_bf16(const float* __restrict__ src,
                                 unsigned short* __restrict__ dst, int n8) {
  int t = blockIdx.x * 256 + threadIdx.x;
  if (t >= n8) return;
  const float4* s = (const float4*)src + (size_t)t * 2;
  float4 a = s[0], b = s[1];
  u16x8 o;
  o[0] = f2bf(a.x); o[1] = f2bf(a.y); o[2] = f2bf(a.z); o[3] = f2bf(a.w);
  o[4] = f2bf(b.x); o[5] = f2bf(b.y); o[6] = f2bf(b.z); o[7] = f2bf(b.w);
  *(u16x8*)(dst + (size_t)t * 8) = o;
}

// ---------------- 256x256 8-phase GEMM: C = A[M][768] * B[N][768]^T (+bias) --
// 8 waves (2M x 4N), BK=64, 12 K-tiles, 128KB LDS (2 K-tile slots).
// T1 XCD swizzle, T2 LDS XOR swizzle (pre-swizzled global source),
// T3/T4 8-phase counted vmcnt, T5 setprio around MFMA.
// OUTMODE 1: bf16 out stride 2304, (acc+bias)*scale (0.125 on Q cols), LDS epilogue.
// OUTMODE 0: fp32 out stride 768, acc+bias, direct stores.

#define SBAR() do { __builtin_amdgcn_sched_barrier(0); __builtin_amdgcn_s_barrier(); } while (0)
#define SBAR2() do { __builtin_amdgcn_sched_barrier(0); __builtin_amdgcn_s_barrier(); __builtin_amdgcn_sched_barrier(0); } while (0)
#define WAITL() do { asm volatile("s_waitcnt lgkmcnt(0)" ::: "memory"); __builtin_amdgcn_sched_barrier(0); } while (0)
#define WAITV(N) asm volatile("s_waitcnt vmcnt(" #N ")" ::: "memory")

template <int OUTMODE>
__global__ __launch_bounds__(512, 2) void gemm256(
    const unsigned short* __restrict__ A, const unsigned short* __restrict__ Bw,
    void* __restrict__ OutP, const float* __restrict__ bias0,
    const float* __restrict__ bias1, const float* __restrict__ bias2) {
  __shared__ __align__(16) char smem[131072];
  const int nwg = gridDim.x;
  const int chunk = nwg >> 3;
  const int swz = ((int)blockIdx.x & 7) * chunk + ((int)blockIdx.x >> 3);
  const int bm = swz % 128, bn = swz / 128;
  const int r0 = bm << 8, c0 = bn << 8;

  const int tid = threadIdx.x;
  const int w = tid >> 6, lane = tid & 63;
  const int wr = w >> 2, wc = w & 3;
  const int lr = lane & 15, lg = lane >> 4;
  const int l8 = lane >> 3, l7 = lane & 7;
  const int swzc = (l7 ^ (l8 & 7)) << 3;  // element offset, pre-swizzled source
  const unsigned short* pa = A + (size_t)(r0 + l8) * EE + swzc;
  const unsigned short* pb = Bw + (size_t)(c0 + l8) * EE + swzc;
  const int j0 = w, j1 = w + 8;

  // ds_read byte offsets
  const int aoff = (wr << 14) + (lr << 7);
  const int boff = 32768 + ((wc >> 1) << 14) + ((wc & 1) << 13) + (lr << 7);
  const int sw0 = ((0 + lg) ^ (lr & 7)) << 4;  // kk=0 col16 = lg
  const int sw1 = ((4 + lg) ^ (lr & 7)) << 4;  // kk=1 col16 = 4+lg

  f32x4 acc[8][4] = {};
  bf16x8 aA[4], aB[4], aC[4], aD[4], bA[4], bB[4];

#define STAGE(s, H, t)                                                        \
  do {                                                                        \
    const unsigned short* _src = ((H) < 2 ? pa : pb) +                        \
        (size_t)(((H) & 1) * 128) * EE + (size_t)(t) * 64;                    \
    char* _d = smem + (s) * 65536 + ((H) >= 2 ? 32768 : 0) + ((H) & 1) * 16384; \
    gload16(_src + (size_t)j0 * 8 * EE, _d + j0 * 1024);                      \
    gload16(_src + (size_t)j1 * 8 * EE, _d + j1 * 1024);                      \
  } while (0)

#define RD_A(dst, g, SW, s)                                                   \
  _Pragma("unroll") for (int _m = 0; _m < 4; ++_m)                            \
      dst[_m] = *(const bf16x8*)(smem + (s) * 65536 + aoff + (g) * 8192 +     \
                                 _m * 2048 + (SW));

#define RD_B(dst, SW, s)                                                      \
  _Pragma("unroll") for (int _n = 0; _n < 4; ++_n)                            \
      dst[_n] = *(const bf16x8*)(smem + (s) * 65536 + boff + _n * 2048 + (SW));

#define MM(g, ar, br)                                                         \
  do {                                                                        \
    __builtin_amdgcn_s_setprio(1);                                            \
    _Pragma("unroll") for (int _i = 0; _i < 4; ++_i)                          \
        _Pragma("unroll") for (int _j = 0; _j < 4; ++_j)                      \
            acc[(g) * 4 + _i][_j] = __builtin_amdgcn_mfma_f32_16x16x32_bf16(  \
                ar[_i], br[_j], acc[(g) * 4 + _i][_j], 0, 0, 0);              \
    __builtin_amdgcn_s_setprio(0);                                            \
  } while (0)

#define ITER(ii, LASTF)                                                        \
  do {                                                                         \
    const int t0 = 2 * (ii), t1 = t0 + 1;                                      \
    /*P0*/ RD_A(aA, 0, sw0, 0); RD_B(bA, sw0, 0); STAGE(1, 1, t1);             \
    SBAR(); WAITL(); MM(0, aA, bA); SBAR2();                                   \
    /*P1*/ RD_A(aB, 1, sw0, 0); RD_A(aC, 0, sw1, 0); STAGE(1, 2, t1);          \
    SBAR(); WAITL(); MM(1, aB, bA); SBAR2();                                   \
    /*P2*/ RD_B(bB, sw1, 0); RD_A(aD, 1, sw1, 0); STAGE(1, 3, t1);             \
    SBAR(); WAITL(); MM(0, aC, bB); SBAR2();                                   \
    /*P3*/ if (!(LASTF)) { STAGE(0, 0, t0 + 2); WAITV(2); } else { WAITV(0); } \
    SBAR(); WAITL(); MM(1, aD, bB); SBAR2();                                   \
    /*P4*/ RD_A(aA, 0, sw0, 1); RD_B(bA, sw0, 1);                              \
    if (!(LASTF)) STAGE(0, 1, t0 + 2);                                         \
    SBAR(); WAITL(); MM(0, aA, bA); SBAR2();                                   \
    /*P5*/ RD_A(aB, 1, sw0, 1); RD_A(aC, 0, sw1, 1);                           \
    if (!(LASTF)) STAGE(0, 2, t0 + 2);                                         \
    SBAR(); WAITL(); MM(1, aB, bA); SBAR2();                                   \
    /*P6*/ RD_B(bB, sw1, 1); RD_A(aD, 1, sw1, 1);                              \
    if (!(LASTF)) STAGE(0, 3, t0 + 2);                                         \
    SBAR(); WAITL(); MM(0, aC, bB); SBAR2();                                   \
    /*P7*/ if (!(LASTF)) { STAGE(1, 0, t1 + 2); WAITV(2); }                    \
    SBAR(); WAITL(); MM(1, aD, bB); SBAR2();                                   \
  } while (0)

  // prologue: tile0 -> slot0 (all 4 half-tiles), tile1 H0 -> slot1
  STAGE(0, 0, 0); STAGE(0, 1, 0); STAGE(0, 2, 0); STAGE(0, 3, 0);
  STAGE(1, 0, 1);
  WAITV(2);
  SBAR2();

#pragma unroll 1
  for (int it = 0; it < 5; ++it) { ITER(it, 0); }
  ITER(5, 1);

#undef STAGE
#undef RD_A
#undef RD_B
#undef MM
#undef ITER

  // ---------------- epilogue ----------------
  if constexpr (OUTMODE == 1) {
    unsigned short* sm = (unsigned short*)smem;
    const int mat = bn / 3;  // 0..8 -> Q,K,V (256-col blocks never straddle)
    const float scale = (mat == 0) ? 0.125f : 1.0f;
    const float* bp = (mat == 0) ? bias0 : (mat == 1 ? bias1 : bias2);
    const int cb = c0 - mat * 768;
    float bv4[4];
#pragma unroll
    for (int n = 0; n < 4; ++n) bv4[n] = bp[cb + (wc << 6) + (n << 4) + lr];
#pragma unroll
    for (int m = 0; m < 8; ++m)
#pragma unroll
      for (int n = 0; n < 4; ++n)
#pragma unroll
        for (int r = 0; r < 4; ++r) {
          int row = (wr << 7) + (m << 4) + (lg << 2) + r;
          int col = (wc << 6) + (n << 4) + lr;
          sm[row * 256 + col] = f2bf((acc[m][n][r] + bv4[n]) * scale);
        }
    __syncthreads();
    unsigned short* out = (unsigned short*)OutP;
#pragma unroll
    for (int p = 0; p < 16; ++p) {
      int idx = p * 512 + tid;
      int row = idx >> 5, c16 = idx & 31;
      *(u16x8*)(out + (size_t)(r0 + row) * NQKV + c0 + c16 * 8) =
          *(const u16x8*)(sm + idx * 8);
    }
  } else {
    float* out = (float*)OutP;
    float bv4[4];
#pragma unroll
    for (int n = 0; n < 4; ++n) bv4[n] = bias0[c0 + (wc << 6) + (n << 4) + lr];
#pragma unroll
    for (int m = 0; m < 8; ++m)
#pragma unroll
      for (int n = 0; n < 4; ++n)
#pragma unroll
        for (int r = 0; r < 4; ++r) {
          int row = (wr << 7) + (m << 4) + (lg << 2) + r;
          int col = (wc << 6) + (n << 4) + lr;
          out[(size_t)(r0 + row) * EE + c0 + col] = acc[m][n][r] + bv4[n];
        }
  }
}

// ---------------- attention per (c,h): 128 queries x 128 keys x 64 dk --------
__global__ __launch_bounds__(256, 2) void attn_kernel(
    const unsigned short* __restrict__ qkv, const unsigned char* __restrict__ pmask,
    float* __restrict__ probs, unsigned short* __restrict__ ctx) {
  __shared__ unsigned short ks[128 * 72];
  __shared__ unsigned short vt[64 * 136];
  __shared__ unsigned short ps[128 * 136];
  const int bx = blockIdx.x;
  const int c = bx / HH, h = bx - (bx / HH) * HH;
  const int tid = threadIdx.x;
  const int wid = tid >> 6, lane = tid & 63;
  const int lr = lane & 15, lg = lane >> 4;
  const int wr = wid;
  const size_t hoff = (size_t)h * DKK;

#pragma unroll
  for (int p = 0; p < 4; ++p) {
    int chunk = p * 256 + tid;
    int j = chunk >> 3, d0 = (chunk & 7) << 3;
    const unsigned short* base = qkv + ((size_t)j * CC + c) * NQKV + hoff;
    bf16x8 kv = *(const bf16x8*)(base + 768 + d0);
    *(bf16x8*)&ks[j * 72 + d0] = kv;
    bf16x8 vv = *(const bf16x8*)(base + 1536 + d0);
#pragma unroll
    for (int u = 0; u < 8; ++u) vt[(d0 + u) * 136 + j] = (unsigned short)vv[u];
  }

  bf16x8 qf[2][2];
#pragma unroll
  for (int m = 0; m < 2; ++m)
#pragma unroll
    for (int kk = 0; kk < 2; ++kk) {
      int qi = (wr << 5) + (m << 4) + lr;
      qf[m][kk] = *(const bf16x8*)(qkv + ((size_t)qi * CC + c) * NQKV + hoff +
                                   kk * 32 + (lg << 3));
    }

  __syncthreads();

  f32x4 s[2][8] = {};
#pragma unroll
  for (int kk = 0; kk < 2; ++kk) {
    bf16x8 kf[8];
#pragma unroll
    for (int n = 0; n < 8; ++n)
      kf[n] = *(const bf16x8*)&ks[(n * 16 + lr) * 72 + kk * 32 + (lg << 3)];
#pragma unroll
    for (int m = 0; m < 2; ++m)
#pragma unroll
      for (int n = 0; n < 8; ++n)
        s[m][n] = __builtin_amdgcn_mfma_f32_16x16x32_bf16(qf[m][kk], kf[n],
                                                          s[m][n], 0, 0, 0);
  }

#pragma unroll
  for (int n = 0; n < 8; ++n) {
    if (pmask[(size_t)(n * 16 + lr) * CC + c] != 0) {
      f32x4 neg = {-10000.0f, -10000.0f, -10000.0f, -10000.0f};
      s[0][n] = neg;
      s[1][n] = neg;
    }
  }

  float inv_[2][4];
#pragma unroll
  for (int m = 0; m < 2; ++m) {
    f32x4 mx = s[m][0];
#pragma unroll
    for (int n = 1; n < 8; ++n)
#pragma unroll
      for (int r = 0; r < 4; ++r) mx[r] = fmaxf(mx[r], s[m][n][r]);
#pragma unroll
    for (int r = 0; r < 4; ++r) {
      float t = mx[r];
      t = fmaxf(t, __shfl_xor(t, 1));
      t = fmaxf(t, __shfl_xor(t, 2));
      t = fmaxf(t, __shfl_xor(t, 4));
      t = fmaxf(t, __shfl_xor(t, 8));
      mx[r] = t;
    }
    f32x4 sum = {};
#pragma unroll
    for (int n = 0; n < 8; ++n)
#pragma unroll
      for (int r = 0; r < 4; ++r) {
        float e = exp2f((s[m][n][r] - mx[r]) * 1.44269504f);
        s[m][n][r] = e;
        sum[r] += e;
      }
#pragma unroll
    for (int r = 0; r < 4; ++r) {
      float t = sum[r];
      t += __shfl_xor(t, 1);
      t += __shfl_xor(t, 2);
      t += __shfl_xor(t, 4);
      t += __shfl_xor(t, 8);
      inv_[m][r] = __builtin_amdgcn_rcpf(t);
    }
  }

  const size_t pbase = ((size_t)h * CC + c) * (size_t)(128 * 128);
#pragma unroll
  for (int m = 0; m < 2; ++m)
#pragma unroll
    for (int n = 0; n < 8; ++n)
#pragma unroll
      for (int r = 0; r < 4; ++r) {
        float pv = s[m][n][r] * inv_[m][r];
        int i = (wr << 5) + (m << 4) + (lg << 2) + r;
        int j = (n << 4) + lr;
        probs[pbase + (size_t)i * 128 + j] = pv;
        ps[i * 136 + j] = f2bf(pv);
      }

  __syncthreads();

  f32x4 o[2][4] = {};
#pragma unroll
  for (int kk = 0; kk < 4; ++kk) {
    bf16x8 pa[2], vb[4];
#pragma unroll
    for (int m = 0; m < 2; ++m)
      pa[m] = *(const bf16x8*)&ps[((wr << 5) + (m << 4) + lr) * 136 + kk * 32 + (lg << 3)];
#pragma unroll
    for (int n = 0; n < 4; ++n)
      vb[n] = *(const bf16x8*)&vt[((n << 4) + lr) * 136 + kk * 32 + (lg << 3)];
#pragma unroll
    for (int m = 0; m < 2; ++m)
#pragma unroll
      for (int n = 0; n < 4; ++n)
        o[m][n] = __builtin_amdgcn_mfma_f32_16x16x32_bf16(pa[m], vb[n], o[m][n], 0, 0, 0);
  }

#pragma unroll
  for (int m = 0; m < 2; ++m)
#pragma unroll
    for (int n = 0; n < 4; ++n)
#pragma unroll
      for (int r = 0; r < 4; ++r) {
        int i = (wr << 5) + (m << 4) + (lg << 2) + r;
        int d = (n << 4) + lr;
        ctx[((size_t)i * CC + c) * EE + hoff + d] = f2bf(o[m][n][r]);
      }
}

extern "C" void kernel_launch(void* const* d_in, const int* in_sizes, int n_in,
                              void* d_out, int out_size, void* d_ws, size_t ws_size,
                              hipStream_t stream) {
  const float* x = (const float*)d_in[0];
  const unsigned char* pm = (const unsigned char*)d_in[1];
  const float* Wq = (const float*)d_in[2];
  const float* bq = (const float*)d_in[3];
  const float* Wk = (const float*)d_in[4];
  const float* bk = (const float*)d_in[5];
  const float* Wv = (const float*)d_in[6];
  const float* bv = (const float*)d_in[7];
  const float* Wo = (const float*)d_in[8];
  const float* bo = (const float*)d_in[9];

  unsigned short* ws = (unsigned short*)d_ws;
  unsigned short* xb = ws;                       // 25165824 el (x_bf16, later ctx)
  unsigned short* qkv = xb + 25165824;           // 75497472 el
  unsigned short* wqkv = qkv + 75497472;         // 1769472 el (Wq|Wk|Wv)
  unsigned short* wo = wqkv + 1769472;           // 589824 el

  float* outp = (float*)d_out;
  float* probs = outp + 25165824;

  cast_f32_to_bf16<<<12288, 256, 0, stream>>>(x, xb, 3145728);
  cast_f32_to_bf16<<<288, 256, 0, stream>>>(Wq, wqkv, 73728);
  cast_f32_to_bf16<<<288, 256, 0, stream>>>(Wk, wqkv + 589824, 73728);
  cast_f32_to_bf16<<<288, 256, 0, stream>>>(Wv, wqkv + 1179648, 73728);
  cast_f32_to_bf16<<<288, 256, 0, stream>>>(Wo, wo, 73728);

  gemm256<1><<<1152, 512, 0, stream>>>(xb, wqkv, (void*)qkv, bq, bk, bv);
  attn_kernel<<<CC * HH, 256, 0, stream>>>(qkv, pm, probs, xb /*ctx*/);
  gemm256<0><<<384, 512, 0, stream>>>(xb, wo, (void*)outp, bo, nullptr, nullptr);
}

// Round 3
// 328.895 us; speedup vs baseline: 1.3386x; 1.0560x over previous
//
#include <hip/hip_runtime.h>
#include <hip/hip_bf16.h>

typedef __attribute__((ext_vector_type(8))) short bf16x8;
typedef __attribute__((ext_vector_type(4))) float f32x4;
typedef __attribute__((ext_vector_type(8))) unsigned short u16x8;

#define RR 128
#define CC 256
#define EE 768
#define HH 12
#define DKK 64
#define NQKV 2304

__device__ __forceinline__ unsigned short f2bf(float f) {
  union { float f; unsigned u; } v; v.f = f;
  unsigned u = v.u;
  unsigned r = (u + 0x7fffu + ((u >> 16) & 1u)) >> 16;
  return (unsigned short)r;
}

__device__ __forceinline__ void gload16(const unsigned short* g, char* l) {
  __builtin_amdgcn_global_load_lds((const __attribute__((address_space(1))) void*)g,
                                   (__attribute__((address_space(3))) void*)l, 16, 0, 0);
}

// ---------------- fused cast fp32 -> bf16 (x + 4 weight matrices) -----------
__global__ void cast_all(const float* __restrict__ x, const float* __restrict__ w0,
                         const float* __restrict__ w1, const float* __restrict__ w2,
                         const float* __restrict__ w3, unsigned short* __restrict__ xb,
                         unsigned short* __restrict__ wdst) {
  int b = blockIdx.x;
  const float* src;
  unsigned short* dst;
  int t;
  if (b < 12288) {
    src = x; dst = xb; t = b * 256 + (int)threadIdx.x;
  } else {
    int bb = b - 12288;
    int m = bb / 288;
    src = (m == 0) ? w0 : (m == 1) ? w1 : (m == 2) ? w2 : w3;
    dst = wdst + (size_t)m * 589824;
    t = (bb - m * 288) * 256 + (int)threadIdx.x;
  }
  const float4* s = (const float4*)src + (size_t)t * 2;
  float4 a = s[0], bq = s[1];
  u16x8 o;
  o[0] = f2bf(a.x); o[1] = f2bf(a.y); o[2] = f2bf(a.z); o[3] = f2bf(a.w);
  o[4] = f2bf(bq.x); o[5] = f2bf(bq.y); o[6] = f2bf(bq.z); o[7] = f2bf(bq.w);
  *(u16x8*)(dst + (size_t)t * 8) = o;
}

// ---------------- 256x256 8-phase GEMM: C = A[M][768] * B[N][768]^T (+bias) --
// OUTMODE 1 (QKV): writes bf16 in attention-native layout [c][h][i][d] per
//   matrix (Q scaled by 0.125), via 128KB LDS epilogue. Tile rows = token range
//   i*256..i*256+255 = {fixed i, c=0..255}, so in-tile row == c.
// OUTMODE 0 (out-proj): A rows are c-major ctx (u = c*128+i); epilogue
//   un-permutes to token-major fp32 out[t*768+col], t = (u&127)<<8 | (u>>7).

#define SBAR() do { __builtin_amdgcn_sched_barrier(0); __builtin_amdgcn_s_barrier(); } while (0)
#define SBAR2() do { __builtin_amdgcn_sched_barrier(0); __builtin_amdgcn_s_barrier(); __builtin_amdgcn_sched_barrier(0); } while (0)
#define WAITL() do { asm volatile("s_waitcnt lgkmcnt(0)" ::: "memory"); __builtin_amdgcn_sched_barrier(0); } while (0)
#define WAITV(N) asm volatile("s_waitcnt vmcnt(" #N ")" ::: "memory")

template <int OUTMODE>
__global__ __launch_bounds__(512, 2) void gemm256(
    const unsigned short* __restrict__ A, const unsigned short* __restrict__ Bw,
    void* __restrict__ OutP, const float* __restrict__ bias0,
    const float* __restrict__ bias1, const float* __restrict__ bias2) {
  __shared__ __align__(16) char smem[131072];
  const int nwg = gridDim.x;
  const int chunk = nwg >> 3;
  const int swz = ((int)blockIdx.x & 7) * chunk + ((int)blockIdx.x >> 3);
  const int bm = swz % 128, bn = swz / 128;
  const int r0 = bm << 8, c0 = bn << 8;

  const int tid = threadIdx.x;
  const int w = tid >> 6, lane = tid & 63;
  const int wr = w >> 2, wc = w & 3;
  const int lr = lane & 15, lg = lane >> 4;
  const int l8 = lane >> 3, l7 = lane & 7;
  const int swzc = (l7 ^ (l8 & 7)) << 3;  // element offset, pre-swizzled source
  const unsigned short* pa = A + (size_t)(r0 + l8) * EE + swzc;
  const unsigned short* pb = Bw + (size_t)(c0 + l8) * EE + swzc;
  const int j0 = w, j1 = w + 8;

  // ds_read byte offsets
  const int aoff = (wr << 14) + (lr << 7);
  const int boff = 32768 + ((wc >> 1) << 14) + ((wc & 1) << 13) + (lr << 7);
  const int sw0 = ((0 + lg) ^ (lr & 7)) << 4;  // kk=0 col16 = lg
  const int sw1 = ((4 + lg) ^ (lr & 7)) << 4;  // kk=1 col16 = 4+lg

  f32x4 acc[8][4] = {};
  bf16x8 aA[4], aB[4], aC[4], aD[4], bA[4], bB[4];

#define STAGE(s, H, t)                                                        \
  do {                                                                        \
    const unsigned short* _src = ((H) < 2 ? pa : pb) +                        \
        (size_t)(((H) & 1) * 128) * EE + (size_t)(t) * 64;                    \
    char* _d = smem + (s) * 65536 + ((H) >= 2 ? 32768 : 0) + ((H) & 1) * 16384; \
    gload16(_src + (size_t)j0 * 8 * EE, _d + j0 * 1024);                      \
    gload16(_src + (size_t)j1 * 8 * EE, _d + j1 * 1024);                      \
  } while (0)

#define RD_A(dst, g, SW, s)                                                   \
  _Pragma("unroll") for (int _m = 0; _m < 4; ++_m)                            \
      dst[_m] = *(const bf16x8*)(smem + (s) * 65536 + aoff + (g) * 8192 +     \
                                 _m * 2048 + (SW));

#define RD_B(dst, SW, s)                                                      \
  _Pragma("unroll") for (int _n = 0; _n < 4; ++_n)                            \
      dst[_n] = *(const bf16x8*)(smem + (s) * 65536 + boff + _n * 2048 + (SW));

#define MM(g, ar, br)                                                         \
  do {                                                                        \
    __builtin_amdgcn_s_setprio(1);                                            \
    _Pragma("unroll") for (int _i = 0; _i < 4; ++_i)                          \
        _Pragma("unroll") for (int _j = 0; _j < 4; ++_j)                      \
            acc[(g) * 4 + _i][_j] = __builtin_amdgcn_mfma_f32_16x16x32_bf16(  \
                ar[_i], br[_j], acc[(g) * 4 + _i][_j], 0, 0, 0);              \
    __builtin_amdgcn_s_setprio(0);                                            \
  } while (0)

#define ITER(ii, LASTF)                                                        \
  do {                                                                         \
    const int t0 = 2 * (ii), t1 = t0 + 1;                                      \
    /*P0*/ RD_A(aA, 0, sw0, 0); RD_B(bA, sw0, 0); STAGE(1, 1, t1);             \
    SBAR(); WAITL(); MM(0, aA, bA); SBAR2();                                   \
    /*P1*/ RD_A(aB, 1, sw0, 0); RD_A(aC, 0, sw1, 0); STAGE(1, 2, t1);          \
    SBAR(); WAITL(); MM(1, aB, bA); SBAR2();                                   \
    /*P2*/ RD_B(bB, sw1, 0); RD_A(aD, 1, sw1, 0); STAGE(1, 3, t1);             \
    SBAR(); WAITL(); MM(0, aC, bB); SBAR2();                                   \
    /*P3*/ if (!(LASTF)) { STAGE(0, 0, t0 + 2); WAITV(2); } else { WAITV(0); } \
    SBAR(); WAITL(); MM(1, aD, bB); SBAR2();                                   \
    /*P4*/ RD_A(aA, 0, sw0, 1); RD_B(bA, sw0, 1);                              \
    if (!(LASTF)) STAGE(0, 1, t0 + 2);                                         \
    SBAR(); WAITL(); MM(0, aA, bA); SBAR2();                                   \
    /*P5*/ RD_A(aB, 1, sw0, 1); RD_A(aC, 0, sw1, 1);                           \
    if (!(LASTF)) STAGE(0, 2, t0 + 2);                                         \
    SBAR(); WAITL(); MM(1, aB, bA); SBAR2();                                   \
    /*P6*/ RD_B(bB, sw1, 1); RD_A(aD, 1, sw1, 1);                              \
    if (!(LASTF)) STAGE(0, 3, t0 + 2);                                         \
    SBAR(); WAITL(); MM(0, aC, bB); SBAR2();                                   \
    /*P7*/ if (!(LASTF)) { STAGE(1, 0, t1 + 2); WAITV(2); }                    \
    SBAR(); WAITL(); MM(1, aD, bB); SBAR2();                                   \
  } while (0)

  STAGE(0, 0, 0); STAGE(0, 1, 0); STAGE(0, 2, 0); STAGE(0, 3, 0);
  STAGE(1, 0, 1);
  WAITV(2);
  SBAR2();

#pragma unroll 1
  for (int it = 0; it < 5; ++it) { ITER(it, 0); }
  ITER(5, 1);

#undef STAGE
#undef RD_A
#undef RD_B
#undef MM
#undef ITER

  // ---------------- epilogue ----------------
  if constexpr (OUTMODE == 1) {
    unsigned short* sm = (unsigned short*)smem;
    const int mat = bn / 3;  // 0..8 -> Q,K,V
    const float scale = (mat == 0) ? 0.125f : 1.0f;
    const float* bp = (mat == 0) ? bias0 : (mat == 1 ? bias1 : bias2);
    const int cb = c0 - mat * 768;
    float bv4[4];
#pragma unroll
    for (int n = 0; n < 4; ++n) bv4[n] = bp[cb + (wc << 6) + (n << 4) + lr];
#pragma unroll
    for (int m = 0; m < 8; ++m)
#pragma unroll
      for (int n = 0; n < 4; ++n)
#pragma unroll
        for (int r = 0; r < 4; ++r) {
          int row = (wr << 7) + (m << 4) + (lg << 2) + r;  // == c
          int col = (wc << 6) + (n << 4) + lr;
          sm[row * 256 + col] = f2bf((acc[m][n][r] + bv4[n]) * scale);
        }
    __syncthreads();
    // store to [c][h][i][d]: addr = ((c*12 + h)*128 + i)*64 + d
    unsigned short* outm = (unsigned short*)OutP + (size_t)mat * 25165824;
    const int hbase = cb >> 6;
    const int i_idx = r0 >> 8;  // fixed i for this tile
#pragma unroll
    for (int p = 0; p < 16; ++p) {
      int idx = p * 512 + tid;         // 8192 chunks of 16B
      int row = idx >> 5;              // c
      int hl = (idx >> 3) & 3;         // head-local (4 heads per 256-col tile)
      int d8 = idx & 7;
      *(u16x8*)(outm + ((((size_t)(row * HH + hbase + hl)) << 7 | i_idx) << 6) + d8 * 8) =
          *(const u16x8*)(sm + row * 256 + hl * 64 + d8 * 8);
    }
  } else {
    float* out = (float*)OutP;
    float bv4[4];
#pragma unroll
    for (int n = 0; n < 4; ++n) bv4[n] = bias0[c0 + (wc << 6) + (n << 4) + lr];
#pragma unroll
    for (int m = 0; m < 8; ++m)
#pragma unroll
      for (int n = 0; n < 4; ++n)
#pragma unroll
        for (int r = 0; r < 4; ++r) {
          int u = r0 + (wr << 7) + (m << 4) + (lg << 2) + r;  // c-major row
          int t = ((u & 127) << 8) | (u >> 7);                 // token
          int col = (wc << 6) + (n << 4) + lr;
          out[(size_t)t * EE + c0 + col] = acc[m][n][r] + bv4[n];
        }
  }
}

// ---------------- attention per (c,h): contiguous Q/K/V blocks ---------------
__global__ __launch_bounds__(256, 2) void attn_kernel(
    const unsigned short* __restrict__ qatt, const unsigned short* __restrict__ katt,
    const unsigned short* __restrict__ vatt, const unsigned char* __restrict__ pmask,
    float* __restrict__ probs, unsigned short* __restrict__ ctx) {
  __shared__ unsigned short ks[128 * 72];
  __shared__ unsigned short vt[64 * 136];
  __shared__ unsigned short ps[128 * 136];
  const int bx = blockIdx.x;
  const int c = bx / HH, h = bx - (bx / HH) * HH;
  const int tid = threadIdx.x;
  const int wid = tid >> 6, lane = tid & 63;
  const int lr = lane & 15, lg = lane >> 4;
  const int wr = wid;
  const size_t blk = ((size_t)(c * HH + h)) << 13;  // *128*64
  const unsigned short* qb = qatt + blk;
  const unsigned short* kb = katt + blk;
  const unsigned short* vb = vatt + blk;

  // stage K (row-major, pad 72) and V^T (pad 136); contiguous 16KB reads each
#pragma unroll
  for (int p = 0; p < 4; ++p) {
    int chunk = p * 256 + tid;
    int j = chunk >> 3, d0 = (chunk & 7) << 3;
    bf16x8 kv = *(const bf16x8*)(kb + j * 64 + d0);
    *(bf16x8*)&ks[j * 72 + d0] = kv;
    bf16x8 vv = *(const bf16x8*)(vb + j * 64 + d0);
#pragma unroll
    for (int u = 0; u < 8; ++u) vt[(d0 + u) * 136 + j] = (unsigned short)vv[u];
  }

  // Q fragments direct from global (contiguous, already scaled)
  bf16x8 qf[2][2];
#pragma unroll
  for (int m = 0; m < 2; ++m)
#pragma unroll
    for (int kk = 0; kk < 2; ++kk) {
      int qi = (wr << 5) + (m << 4) + lr;
      qf[m][kk] = *(const bf16x8*)(qb + qi * 64 + kk * 32 + (lg << 3));
    }

  __syncthreads();

  f32x4 s[2][8] = {};
#pragma unroll
  for (int kk = 0; kk < 2; ++kk) {
    bf16x8 kf[8];
#pragma unroll
    for (int n = 0; n < 8; ++n)
      kf[n] = *(const bf16x8*)&ks[(n * 16 + lr) * 72 + kk * 32 + (lg << 3)];
#pragma unroll
    for (int m = 0; m < 2; ++m)
#pragma unroll
      for (int n = 0; n < 8; ++n)
        s[m][n] = __builtin_amdgcn_mfma_f32_16x16x32_bf16(qf[m][kk], kf[n],
                                                          s[m][n], 0, 0, 0);
  }

#pragma unroll
  for (int n = 0; n < 8; ++n) {
    if (pmask[(size_t)(n * 16 + lr) * CC + c] != 0) {
      f32x4 neg = {-10000.0f, -10000.0f, -10000.0f, -10000.0f};
      s[0][n] = neg;
      s[1][n] = neg;
    }
  }

  float inv_[2][4];
#pragma unroll
  for (int m = 0; m < 2; ++m) {
    f32x4 mx = s[m][0];
#pragma unroll
    for (int n = 1; n < 8; ++n)
#pragma unroll
      for (int r = 0; r < 4; ++r) mx[r] = fmaxf(mx[r], s[m][n][r]);
#pragma unroll
    for (int r = 0; r < 4; ++r) {
      float t = mx[r];
      t = fmaxf(t, __shfl_xor(t, 1));
      t = fmaxf(t, __shfl_xor(t, 2));
      t = fmaxf(t, __shfl_xor(t, 4));
      t = fmaxf(t, __shfl_xor(t, 8));
      mx[r] = t;
    }
    f32x4 sum = {};
#pragma unroll
    for (int n = 0; n < 8; ++n)
#pragma unroll
      for (int r = 0; r < 4; ++r) {
        float e = exp2f((s[m][n][r] - mx[r]) * 1.44269504f);
        s[m][n][r] = e;
        sum[r] += e;
      }
#pragma unroll
    for (int r = 0; r < 4; ++r) {
      float t = sum[r];
      t += __shfl_xor(t, 1);
      t += __shfl_xor(t, 2);
      t += __shfl_xor(t, 4);
      t += __shfl_xor(t, 8);
      inv_[m][r] = __builtin_amdgcn_rcpf(t);
    }
  }

  const size_t pbase = ((size_t)h * CC + c) * (size_t)(128 * 128);
#pragma unroll
  for (int m = 0; m < 2; ++m)
#pragma unroll
    for (int n = 0; n < 8; ++n)
#pragma unroll
      for (int r = 0; r < 4; ++r) {
        float pv = s[m][n][r] * inv_[m][r];
        int i = (wr << 5) + (m << 4) + (lg << 2) + r;
        int j = (n << 4) + lr;
        probs[pbase + (size_t)i * 128 + j] = pv;
        ps[i * 136 + j] = f2bf(pv);
      }

  __syncthreads();

  f32x4 o[2][4] = {};
#pragma unroll
  for (int kk = 0; kk < 4; ++kk) {
    bf16x8 pa[2], vbr[4];
#pragma unroll
    for (int m = 0; m < 2; ++m)
      pa[m] = *(const bf16x8*)&ps[((wr << 5) + (m << 4) + lr) * 136 + kk * 32 + (lg << 3)];
#pragma unroll
    for (int n = 0; n < 4; ++n)
      vbr[n] = *(const bf16x8*)&vt[((n << 4) + lr) * 136 + kk * 32 + (lg << 3)];
#pragma unroll
    for (int m = 0; m < 2; ++m)
#pragma unroll
      for (int n = 0; n < 4; ++n)
        o[m][n] = __builtin_amdgcn_mfma_f32_16x16x32_bf16(pa[m], vbr[n], o[m][n], 0, 0, 0);
  }

  // ctx (c-major [c*128+i][768]) via LDS bounce for 16B stores.
  // ks region is dead (last read before the pre-PV barrier) -> reuse.
  unsigned short* cbuf = ks;
#pragma unroll
  for (int m = 0; m < 2; ++m)
#pragma unroll
    for (int n = 0; n < 4; ++n)
#pragma unroll
      for (int r = 0; r < 4; ++r) {
        int i = (wr << 5) + (m << 4) + (lg << 2) + r;
        int d = (n << 4) + lr;
        cbuf[i * 64 + d] = f2bf(o[m][n][r]);
      }
  __syncthreads();
#pragma unroll
  for (int p = 0; p < 4; ++p) {
    int chunk = p * 256 + tid;
    int i = chunk >> 3, d8 = chunk & 7;
    *(u16x8*)(ctx + ((size_t)c * 128 + i) * EE + h * 64 + d8 * 8) =
        *(const u16x8*)(cbuf + i * 64 + d8 * 8);
  }
}

extern "C" void kernel_launch(void* const* d_in, const int* in_sizes, int n_in,
                              void* d_out, int out_size, void* d_ws, size_t ws_size,
                              hipStream_t stream) {
  const float* x = (const float*)d_in[0];
  const unsigned char* pm = (const unsigned char*)d_in[1];
  const float* Wq = (const float*)d_in[2];
  const float* bq = (const float*)d_in[3];
  const float* Wk = (const float*)d_in[4];
  const float* bk = (const float*)d_in[5];
  const float* Wv = (const float*)d_in[6];
  const float* bv = (const float*)d_in[7];
  const float* Wo = (const float*)d_in[8];
  const float* bo = (const float*)d_in[9];

  unsigned short* ws = (unsigned short*)d_ws;
  unsigned short* xb = ws;                       // 25165824 (x_bf16, later ctx c-major)
  unsigned short* qkv = xb + 25165824;           // 3 x 25165824 ([c][h][i][d] per matrix)
  unsigned short* wcast = qkv + 75497472;        // 4 x 589824 (Wq|Wk|Wv|Wo)

  float* outp = (float*)d_out;
  float* probs = outp + 25165824;

  cast_all<<<13440, 256, 0, stream>>>(x, Wq, Wk, Wv, Wo, xb, wcast);
  gemm256<1><<<1152, 512, 0, stream>>>(xb, wcast, (void*)qkv, bq, bk, bv);
  attn_kernel<<<CC * HH, 256, 0, stream>>>(qkv, qkv + 25165824, qkv + 50331648,
                                           pm, probs, xb /*ctx c-major*/);
  gemm256<0><<<384, 512, 0, stream>>>(xb, wcast + 1769472, (void*)outp, bo,
                                      nullptr, nullptr);
}